// Round 7
// baseline (188.119 us; speedup 1.0000x reference)
//
#include <hip/hip_runtime.h>

// RoiCropper: image [B=8, D=128, H=128, W=128, C=1] f32, boxes [B, N=128, 3] i32
// out [B, N, 32, 32, 32, 1] f32
// out[b,n,z,y,x] = image[b, bz+z, by+y, bx+x] with starts clamped to [0, dim-32]
// (lax.dynamic_slice clamp semantics).
//
// Round 7: ZPB 8 -> 16 (grid 4096 -> 2048, one block per half-crop).
// Doubles per-thread work: 16 in-flight 16B loads/thread, box-load +
// address setup amortized 2x. Still 8 resident blocks/CU (32 waves).
// Keeps round-6 dwordx4 under-aligned loads + nontemporal stores.
// If this is null (+-3us), kernel is at its compulsory-traffic floor.

#define BB 8
#define NN 128
#define DD 128
#define HH 128
#define WW 128
#define RR 32
#define ZPB 16  // z-slabs per block

typedef float f32x4 __attribute__((ext_vector_type(4)));
typedef f32x4 __attribute__((aligned(4))) f32x4_u;  // under-aligned view

__global__ __launch_bounds__(256) void RoiCropper_79542794322056_kernel(
    const float* __restrict__ image,
    const int* __restrict__ boxes,
    float* __restrict__ out) {
  const int blk = blockIdx.x;         // bn*2 + zh
  const int zh = blk & 1;             // which z-half (16 slabs each)
  const int bn = blk >> 1;            // b*N + n, 0..1023
  const int b = bn >> 7;              // bn / 128

  // Box start corner (block-uniform -> scalar loads).
  int bz = boxes[bn * 3 + 0];
  int by = boxes[bn * 3 + 1];
  int bx = boxes[bn * 3 + 2];
  // dynamic_slice clamps start so the slice stays in-bounds.
  bz = min(max(bz, 0), DD - RR);
  by = min(max(by, 0), HH - RR);
  bx = min(max(bx, 0), WW - RR);

  // Thread t covers (y = t/8, x = (t%8)*4 .. +3) within each 32x32 z-slab.
  const int t = threadIdx.x;
  const int y = t >> 3;
  const int x4 = (t & 7) << 2;

  const int z0 = zh * ZPB;
  const float* src =
      image + (((size_t)b * DD + (size_t)(bz + z0)) * HH + (size_t)(by + y)) * WW +
      (size_t)(bx + x4);
  float* dst =
      out + ((((size_t)bn * RR + z0) * RR + y) * RR) + (size_t)x4;

#pragma unroll
  for (int zi = 0; zi < ZPB; ++zi) {
    // Dword-aligned (not 16B-aligned) 16-byte load; gfx950 handles it.
    f32x4 v = *reinterpret_cast<const f32x4_u*>(src + (size_t)zi * (HH * WW));
    // Output row base is a multiple of 32 floats -> 16B-aligned at +x4.
    __builtin_nontemporal_store(v, reinterpret_cast<f32x4*>(dst + zi * (RR * RR)));
  }
}

extern "C" void kernel_launch(void* const* d_in, const int* in_sizes, int n_in,
                              void* d_out, int out_size, void* d_ws, size_t ws_size,
                              hipStream_t stream) {
  const float* image = (const float*)d_in[0];
  const int* boxes = (const int*)d_in[1];
  float* out = (float*)d_out;

  const int grid = BB * NN * (RR / ZPB);  // 2048
  RoiCropper_79542794322056_kernel<<<grid, 256, 0, stream>>>(image, boxes, out);
}